// Round 1
// baseline (364.594 us; speedup 1.0000x reference)
//
#include <hip/hip_runtime.h>
#include <math.h>

// Problem constants (fixed by reference): B=4, C=64, H=W=64 -> N=4096, CQK=8
#define NPIX 4096

// ---------------------------------------------------------------------------
// Kernel 1: fused 1x1-conv QKV projection.
// q,k: [B*N, 8]  v: [B*N, 64]  (pixel-major so the flash kernel loads rows)
// One thread per pixel; weights staged in LDS (broadcast reads, conflict-free).
// ---------------------------------------------------------------------------
__global__ __launch_bounds__(64) void qkv_kernel(
    const float* __restrict__ x,
    const float* __restrict__ Wq, const float* __restrict__ bq,
    const float* __restrict__ Wk, const float* __restrict__ bk,
    const float* __restrict__ Wv, const float* __restrict__ bv,
    float* __restrict__ qb, float* __restrict__ kb, float* __restrict__ vb)
{
    __shared__ float sWq[512];
    __shared__ float sWk[512];
    __shared__ float sWv[4096];
    __shared__ float sb[80];      // [0:8)=bq  [8:16)=bk  [16:80)=bv

    int tid = threadIdx.x;
    for (int i = tid; i < 512; i += 64) { sWq[i] = Wq[i]; sWk[i] = Wk[i]; }
    for (int i = tid; i < 4096; i += 64) sWv[i] = Wv[i];
    if (tid < 8) { sb[tid] = bq[tid]; sb[8 + tid] = bk[tid]; }
    sb[16 + tid] = bv[tid];
    __syncthreads();

    int gid = blockIdx.x * 64 + tid;          // 0 .. B*N-1
    int b = gid >> 12;
    int n = gid & (NPIX - 1);

    const float* xp = x + ((size_t)b << 18) + n;   // x[b, c, n], stride N over c
    float xv[64];
#pragma unroll
    for (int c = 0; c < 64; ++c) xv[c] = xp[(size_t)c << 12];

    // ---- q and k (8 outputs each) ----
    float qo[8], ko[8];
#pragma unroll
    for (int o = 0; o < 8; ++o) {
        float aq = sb[o];
        float ak = sb[8 + o];
#pragma unroll
        for (int c4 = 0; c4 < 16; ++c4) {
            float4 wq = *(const float4*)&sWq[o * 64 + c4 * 4];
            float4 wk = *(const float4*)&sWk[o * 64 + c4 * 4];
            float x0 = xv[c4 * 4 + 0], x1 = xv[c4 * 4 + 1];
            float x2 = xv[c4 * 4 + 2], x3 = xv[c4 * 4 + 3];
            aq = fmaf(wq.x, x0, fmaf(wq.y, x1, fmaf(wq.z, x2, fmaf(wq.w, x3, aq))));
            ak = fmaf(wk.x, x0, fmaf(wk.y, x1, fmaf(wk.z, x2, fmaf(wk.w, x3, ak))));
        }
        qo[o] = aq; ko[o] = ak;
    }
    float4* qout = (float4*)(qb + (size_t)gid * 8);
    qout[0] = make_float4(qo[0], qo[1], qo[2], qo[3]);
    qout[1] = make_float4(qo[4], qo[5], qo[6], qo[7]);
    float4* kout = (float4*)(kb + (size_t)gid * 8);
    kout[0] = make_float4(ko[0], ko[1], ko[2], ko[3]);
    kout[1] = make_float4(ko[4], ko[5], ko[6], ko[7]);

    // ---- v (64 outputs), 4 at a time ----
    float* vout = vb + (size_t)gid * 64;
#pragma unroll
    for (int og = 0; og < 16; ++og) {
        float a0 = sb[16 + og * 4 + 0];
        float a1 = sb[16 + og * 4 + 1];
        float a2 = sb[16 + og * 4 + 2];
        float a3 = sb[16 + og * 4 + 3];
#pragma unroll
        for (int c4 = 0; c4 < 16; ++c4) {
            float x0 = xv[c4 * 4 + 0], x1 = xv[c4 * 4 + 1];
            float x2 = xv[c4 * 4 + 2], x3 = xv[c4 * 4 + 3];
            float4 w0 = *(const float4*)&sWv[(og * 4 + 0) * 64 + c4 * 4];
            float4 w1 = *(const float4*)&sWv[(og * 4 + 1) * 64 + c4 * 4];
            float4 w2 = *(const float4*)&sWv[(og * 4 + 2) * 64 + c4 * 4];
            float4 w3 = *(const float4*)&sWv[(og * 4 + 3) * 64 + c4 * 4];
            a0 = fmaf(w0.x, x0, fmaf(w0.y, x1, fmaf(w0.z, x2, fmaf(w0.w, x3, a0))));
            a1 = fmaf(w1.x, x0, fmaf(w1.y, x1, fmaf(w1.z, x2, fmaf(w1.w, x3, a1))));
            a2 = fmaf(w2.x, x0, fmaf(w2.y, x1, fmaf(w2.z, x2, fmaf(w2.w, x3, a2))));
            a3 = fmaf(w3.x, x0, fmaf(w3.y, x1, fmaf(w3.z, x2, fmaf(w3.w, x3, a3))));
        }
        *(float4*)(vout + og * 4) = make_float4(a0, a1, a2, a3);
    }
}

// ---------------------------------------------------------------------------
// Kernel 2: flash-style attention + residual.
// Grid: B * (N/64) = 256 blocks, 256 threads each.
// Block owns 64 queries. Thread (qg=tid/16, cg=tid&15) owns a 4-query x
// 4-channel accumulator tile. Online softmax state per query (replicated
// across the 16 cg lanes of its row group; reductions via shfl_xor 1/2/4/8,
// all intra-wave since wave=64).
// ---------------------------------------------------------------------------
__global__ __launch_bounds__(256) void flash_kernel(
    const float* __restrict__ qb, const float* __restrict__ kb,
    const float* __restrict__ vb, const float* __restrict__ x,
    const float* __restrict__ gamma, float* __restrict__ out)
{
    __shared__ float Ks[64 * 8];       // K tile [j][d]
    __shared__ float Vs[64 * 64];      // V tile [j][c]  (reused as Out tile)
    __shared__ float pT[64][68];       // P transposed [j][i], pad 68 breaks bank stride

    int tid = threadIdx.x;
    int qg = tid >> 4;                 // 0..15 query group
    int cg = tid & 15;                 // 0..15 channel group
    int b  = blockIdx.x >> 6;
    int i0 = (blockIdx.x & 63) << 6;

    // load this thread's 4 query vectors (8 floats each) straight from global
    float qr[4][8];
#pragma unroll
    for (int a = 0; a < 4; ++a) {
        const float4* qp = (const float4*)(qb + (size_t)(b * NPIX + i0 + qg * 4 + a) * 8);
        float4 q0 = qp[0], q1 = qp[1];
        qr[a][0] = q0.x; qr[a][1] = q0.y; qr[a][2] = q0.z; qr[a][3] = q0.w;
        qr[a][4] = q1.x; qr[a][5] = q1.y; qr[a][6] = q1.z; qr[a][7] = q1.w;
    }

    float m[4], l[4], acc[4][4];
#pragma unroll
    for (int a = 0; a < 4; ++a) {
        m[a] = -INFINITY; l[a] = 0.f;
#pragma unroll
        for (int cc = 0; cc < 4; ++cc) acc[a][cc] = 0.f;
    }

    const float4* kbase = (const float4*)(kb + (size_t)b * NPIX * 8);
    const float4* vbase = (const float4*)(vb + (size_t)b * NPIX * 64);

    for (int t = 0; t < 64; ++t) {
        int j0 = t << 6;
        __syncthreads();   // previous tile's Vs/pT reads done before restage
        if (tid < 128) ((float4*)Ks)[tid] = kbase[j0 * 2 + tid];
#pragma unroll
        for (int u = 0; u < 4; ++u)
            ((float4*)Vs)[tid + u * 256] = vbase[j0 * 16 + tid + u * 256];
        __syncthreads();

        // scores for own (4 queries) x (4 j's)
        float p[4][4];
        float rmax[4] = {-INFINITY, -INFINITY, -INFINITY, -INFINITY};
#pragma unroll
        for (int jb = 0; jb < 4; ++jb) {
            int j = cg * 4 + jb;
            float4 k0 = *(const float4*)&Ks[j * 8];
            float4 k1 = *(const float4*)&Ks[j * 8 + 4];
#pragma unroll
            for (int a = 0; a < 4; ++a) {
                float s = fmaf(qr[a][0], k0.x, fmaf(qr[a][1], k0.y,
                          fmaf(qr[a][2], k0.z, fmaf(qr[a][3], k0.w,
                          fmaf(qr[a][4], k1.x, fmaf(qr[a][5], k1.y,
                          fmaf(qr[a][6], k1.z, qr[a][7] * k1.w)))))));
                p[a][jb] = s;
                rmax[a] = fmaxf(rmax[a], s);
            }
        }
        // row max over the 16 cg lanes
#pragma unroll
        for (int a = 0; a < 4; ++a) {
            float v1 = rmax[a];
            v1 = fmaxf(v1, __shfl_xor(v1, 1, 64));
            v1 = fmaxf(v1, __shfl_xor(v1, 2, 64));
            v1 = fmaxf(v1, __shfl_xor(v1, 4, 64));
            v1 = fmaxf(v1, __shfl_xor(v1, 8, 64));
            rmax[a] = v1;
        }
        float alpha[4], rsum[4];
#pragma unroll
        for (int a = 0; a < 4; ++a) {
            float mn = fmaxf(m[a], rmax[a]);
            alpha[a] = __expf(m[a] - mn);   // m=-inf first tile -> alpha=0
            m[a] = mn;
            float s0 = 0.f;
#pragma unroll
            for (int jb = 0; jb < 4; ++jb) {
                float e = __expf(p[a][jb] - mn);
                p[a][jb] = e;
                s0 += e;
            }
            rsum[a] = s0;
        }
#pragma unroll
        for (int a = 0; a < 4; ++a) {
            float s0 = rsum[a];
            s0 += __shfl_xor(s0, 1, 64);
            s0 += __shfl_xor(s0, 2, 64);
            s0 += __shfl_xor(s0, 4, 64);
            s0 += __shfl_xor(s0, 8, 64);
            l[a] = fmaf(l[a], alpha[a], s0);
#pragma unroll
            for (int cc = 0; cc < 4; ++cc) acc[a][cc] *= alpha[a];
        }
        // publish P (transposed: [j][i]) — consumers are in the same wave,
        // but keep the barrier for safety this round
#pragma unroll
        for (int jb = 0; jb < 4; ++jb) {
            int j = cg * 4 + jb;
            *(float4*)&pT[j][qg * 4] = make_float4(p[0][jb], p[1][jb], p[2][jb], p[3][jb]);
        }
        __syncthreads();

        // accumulate: each ds_read_b128 of V feeds 8 FMAs (4q reuse + 4c)
#pragma unroll 4
        for (int j = 0; j < 64; ++j) {
            float4 pj = *(const float4*)&pT[j][qg * 4];
            float4 vj = *(const float4*)&Vs[j * 64 + cg * 4];
            float pa[4] = {pj.x, pj.y, pj.z, pj.w};
            float va[4] = {vj.x, vj.y, vj.z, vj.w};
#pragma unroll
            for (int a = 0; a < 4; ++a)
#pragma unroll
                for (int cc = 0; cc < 4; ++cc)
                    acc[a][cc] = fmaf(pa[a], va[cc], acc[a][cc]);
        }
    }

    // epilogue: normalize, transpose through LDS, coalesced residual store
    __syncthreads();
#pragma unroll
    for (int a = 0; a < 4; ++a) {
        float inv = 1.0f / l[a];
#pragma unroll
        for (int cc = 0; cc < 4; ++cc)
            Vs[(cg * 4 + cc) * 64 + qg * 4 + a] = acc[a][cc] * inv;
    }
    __syncthreads();
    float g = gamma[0];
    const float* xb = x + ((size_t)b << 18) + i0;
    float*       ob = out + ((size_t)b << 18) + i0;
#pragma unroll
    for (int u = 0; u < 16; ++u) {
        int idx = tid + u * 256;
        int c = idx >> 6, ii = idx & 63;
        size_t off = ((size_t)c << 12) + ii;
        ob[off] = fmaf(g, Vs[idx], xb[off]);
    }
}

extern "C" void kernel_launch(void* const* d_in, const int* in_sizes, int n_in,
                              void* d_out, int out_size, void* d_ws, size_t ws_size,
                              hipStream_t stream) {
    const float* x     = (const float*)d_in[0];
    const float* Wq    = (const float*)d_in[1];
    const float* bq    = (const float*)d_in[2];
    const float* Wk    = (const float*)d_in[3];
    const float* bk    = (const float*)d_in[4];
    const float* Wv    = (const float*)d_in[5];
    const float* bv    = (const float*)d_in[6];
    const float* gamma = (const float*)d_in[7];
    float* out = (float*)d_out;

    // workspace layout (floats): q [16384*8] | k [16384*8] | v [16384*64]
    float* qb = (float*)d_ws;
    float* kb = qb + (size_t)4 * NPIX * 8;
    float* vb = kb + (size_t)4 * NPIX * 8;

    qkv_kernel<<<256, 64, 0, stream>>>(x, Wq, bq, Wk, bk, Wv, bv, qb, kb, vb);
    flash_kernel<<<256, 256, 0, stream>>>(qb, kb, vb, x, gamma, out);
}

// Round 2
// 143.113 us; speedup vs baseline: 2.5476x; 2.5476x over previous
//
#include <hip/hip_runtime.h>
#include <hip/hip_bf16.h>
#include <math.h>

#define NPIX 4096

typedef __attribute__((ext_vector_type(8))) short s8;   // 8 x bf16 (4 VGPRs)
typedef __attribute__((ext_vector_type(4))) float f4;   // 4 x f32

// ---------------------------------------------------------------------------
// Kernel 1: prep — q,k projections (bf16) + bf16 copy of x.
// qbf,kbf: [B*N][8] bf16 (pixel-major).  xbf: [B][64][4096] bf16 (same layout as x).
// Grid 256 x 256: block = (b, 64-pixel tile). x tile staged in LDS fp32.
// ---------------------------------------------------------------------------
__global__ __launch_bounds__(256) void prep_kernel(
    const float* __restrict__ x,
    const float* __restrict__ Wq, const float* __restrict__ bq,
    const float* __restrict__ Wk, const float* __restrict__ bk,
    __hip_bfloat16* __restrict__ qbf, __hip_bfloat16* __restrict__ kbf,
    __hip_bfloat16* __restrict__ xbf)
{
    __shared__ float Xp[64][65];     // +1 pad: column reads (c+lane)%32 -> 2-way (free)
    int t = threadIdx.x;
    int lane = t & 63;
    int grp  = t >> 6;               // 0..3
    int b  = blockIdx.x >> 6;
    int n0 = (blockIdx.x & 63) << 6;

    const float* xb = x + ((size_t)b << 18);
    __hip_bfloat16* xbb = xbf + ((size_t)b << 18);
#pragma unroll
    for (int u = 0; u < 16; ++u) {
        int c = grp + u * 4;
        float v = xb[((size_t)c << 12) + n0 + lane];   // coalesced 256B/row
        Xp[c][lane] = v;
        xbb[((size_t)c << 12) + n0 + lane] = __float2bfloat16(v);
    }
    __syncthreads();

    int o0 = grp * 2, o1 = o0 + 1;
    float qa0 = bq[o0], qa1 = bq[o1], ka0 = bk[o0], ka1 = bk[o1];
    const float* wq0 = Wq + o0 * 64; const float* wq1 = Wq + o1 * 64;
    const float* wk0 = Wk + o0 * 64; const float* wk1 = Wk + o1 * 64;
#pragma unroll
    for (int c = 0; c < 64; ++c) {   // weight reads wave-uniform -> scalar path
        float xv = Xp[c][lane];
        qa0 = fmaf(wq0[c], xv, qa0);
        qa1 = fmaf(wq1[c], xv, qa1);
        ka0 = fmaf(wk0[c], xv, ka0);
        ka1 = fmaf(wk1[c], xv, ka1);
    }
    int pix = b * NPIX + n0 + lane;
    __hip_bfloat162 qp = __float22bfloat162_rn(make_float2(qa0, qa1));
    __hip_bfloat162 kp = __float22bfloat162_rn(make_float2(ka0, ka1));
    *(__hip_bfloat162*)(qbf + (size_t)pix * 8 + o0) = qp;
    *(__hip_bfloat162*)(kbf + (size_t)pix * 8 + o0) = kp;
}

// ---------------------------------------------------------------------------
// Kernel 2: MFMA flash attention + deferred V projection + residual.
// Grid 256 (b, 64-query tile i0), 256 threads = 4 waves.
// Per 128-j tile: wave w owns j-stripe [w*32, w*32+32).
//   S^T = K·Q^T via mfma 16x16x32 bf16 (k = d = 8, zero-padded via Q-frag).
//   Per-wave online softmax over its stripes; P routed C-layout -> A-layout
//   through per-wave private LDS (same-wave, no barrier).
//   out2[c][i] += x[c][j]·P^T[j][i] via mfma (k = 32 = stripe).
// Epilogue: flash-merge the 4 per-wave partials, then out = gamma*(Wv·out2/l + bv) + x.
// ---------------------------------------------------------------------------
__global__ __launch_bounds__(256, 1) void flash_kernel(
    const __hip_bfloat16* __restrict__ qbf, const __hip_bfloat16* __restrict__ kbf,
    const __hip_bfloat16* __restrict__ xbf,
    const float* __restrict__ Wv, const float* __restrict__ bv,
    const float* __restrict__ x, const float* __restrict__ gamma,
    float* __restrict__ out)
{
    // pool phase A: Xs [64][136] bf16 @0 (17408B) | PT[w] [64][40] bf16 @17408+w*5120 (20480B)
    // pool phase B: Osh [64][68] f32 @0 | Msh @17408 | Lsh @18432 | Linv @19456 | Wvs @19712 | bvs @36096
    __shared__ __align__(16) char pool[37888];
    unsigned short* Xs = (unsigned short*)pool;

    int t = threadIdx.x;
    int w    = t >> 6;
    int lane = t & 63;
    int quad = lane >> 4;
    int c16  = lane & 15;
    unsigned short* PTw = (unsigned short*)(pool + 17408 + w * 5120);

    int b  = blockIdx.x >> 6;
    int i0 = (blockIdx.x & 63) << 6;

    const s8 zero8 = {0, 0, 0, 0, 0, 0, 0, 0};
    const f4 zero4 = {0.f, 0.f, 0.f, 0.f};

    // Q B-frags, loaded once. B[k=quad*8+dd][n=c16] = q[i][d]; only quad0 holds real d (0..7).
    s8 qf[4];
#pragma unroll
    for (int it = 0; it < 4; ++it) {
        s8 qv = *(const s8*)(qbf + ((size_t)(b * NPIX + i0 + it * 16 + c16) << 3));
        qf[it] = (quad == 0) ? qv : zero8;
    }

    f4 acc[4][4];
    float m[4], l[4];
#pragma unroll
    for (int it = 0; it < 4; ++it) {
        m[it] = -INFINITY; l[it] = 0.f;
#pragma unroll
        for (int cm = 0; cm < 4; ++cm) acc[cm][it] = zero4;
    }

    const __hip_bfloat16* kb = kbf + ((size_t)(b * NPIX) << 3);
    const unsigned short* xg = (const unsigned short*)xbf + ((size_t)b << 18);

    for (int tile = 0; tile < 32; ++tile) {
        int j0 = tile << 7;
        // K A-frags from global (prefetch before barrier; quads 1..3 read harmless
        // finite garbage — multiplied by the zeroed Q-frag k-rows).
        s8 kf0 = *(const s8*)(kb + ((size_t)(j0 + w * 32 + c16) << 3));
        s8 kf1 = *(const s8*)(kb + ((size_t)(j0 + w * 32 + 16 + c16) << 3));

        __syncthreads();   // previous tile's Xs reads done
        {
            int c = t >> 2, seg = t & 3;
            const uint4* src = (const uint4*)(xg + ((size_t)c << 12) + j0 + seg * 32);
            uint4* dst = (uint4*)(Xs + c * 136 + seg * 32);
#pragma unroll
            for (int u = 0; u < 4; ++u) dst[u] = src[u];
        }
        __syncthreads();

        // scores S^T chunk [32 j x 64 i]
        f4 s[2][4];
#pragma unroll
        for (int it = 0; it < 4; ++it) {
            s[0][it] = __builtin_amdgcn_mfma_f32_16x16x32_bf16(kf0, qf[it], zero4, 0, 0, 0);
            s[1][it] = __builtin_amdgcn_mfma_f32_16x16x32_bf16(kf1, qf[it], zero4, 0, 0, 0);
        }

        // online softmax per column i = it*16+c16; rows live in (jm, quad, reg)
#pragma unroll
        for (int it = 0; it < 4; ++it) {
            float cmax = fmaxf(
                fmaxf(fmaxf(s[0][it][0], s[0][it][1]), fmaxf(s[0][it][2], s[0][it][3])),
                fmaxf(fmaxf(s[1][it][0], s[1][it][1]), fmaxf(s[1][it][2], s[1][it][3])));
            cmax = fmaxf(cmax, __shfl_xor(cmax, 16));
            cmax = fmaxf(cmax, __shfl_xor(cmax, 32));
            float mnew = fmaxf(m[it], cmax);
            float alpha = __expf(m[it] - mnew);
            float p[2][4];
            float rsum = 0.f;
#pragma unroll
            for (int jm = 0; jm < 2; ++jm)
#pragma unroll
                for (int r = 0; r < 4; ++r) {
                    float e = __expf(s[jm][it][r] - mnew);
                    p[jm][r] = e;
                    rsum += e;
                }
            rsum += __shfl_xor(rsum, 16);
            rsum += __shfl_xor(rsum, 32);
            l[it] = fmaf(l[it], alpha, rsum);
            m[it] = mnew;
#pragma unroll
            for (int cm = 0; cm < 4; ++cm) acc[cm][it] *= alpha;

            // publish P^T chunk to private LDS: PT[i][j], j = jm*16 + quad*4 + r
            int i = it * 16 + c16;
#pragma unroll
            for (int jm = 0; jm < 2; ++jm) {
                __hip_bfloat162 lo = __float22bfloat162_rn(make_float2(p[jm][0], p[jm][1]));
                __hip_bfloat162 hi = __float22bfloat162_rn(make_float2(p[jm][2], p[jm][3]));
                union { __hip_bfloat162 h2; unsigned u; } cl, ch;
                cl.h2 = lo; ch.h2 = hi;
                uint2 pk; pk.x = cl.u; pk.y = ch.u;
                *(uint2*)(PTw + i * 40 + jm * 16 + quad * 4) = pk;
            }
        }

        // P·x: B-frags from PT (same wave — lgkmcnt only), A-frags from Xs
        s8 pf[4];
#pragma unroll
        for (int it = 0; it < 4; ++it)
            pf[it] = *(const s8*)(PTw + (it * 16 + c16) * 40 + quad * 8);
#pragma unroll
        for (int cm = 0; cm < 4; ++cm) {
            s8 xf = *(const s8*)(Xs + (cm * 16 + c16) * 136 + w * 32 + quad * 8);
#pragma unroll
            for (int it = 0; it < 4; ++it)
                acc[cm][it] = __builtin_amdgcn_mfma_f32_16x16x32_bf16(xf, pf[it], acc[cm][it], 0, 0, 0);
        }
    }

    // ---------------- epilogue: merge 4 per-wave partials ----------------
    float* Osh  = (float*)pool;                  // [64 i][68]
    float* Msh  = (float*)(pool + 17408);        // [4][64]
    float* Lsh  = (float*)(pool + 18432);        // [4][64]
    float* Linv = (float*)(pool + 19456);        // [64]
    float* Wvs  = (float*)(pool + 19712);        // [64][64]
    float* bvs  = (float*)(pool + 36096);        // [64]

    __syncthreads();   // everyone done with Xs/PT
    if (quad == 0) {
#pragma unroll
        for (int it = 0; it < 4; ++it) {
            Msh[w * 64 + it * 16 + c16] = m[it];
            Lsh[w * 64 + it * 16 + c16] = l[it];
        }
    }
    {   // stage Wv, bv (region overlaps dead PT buffers — after barrier above)
        const float4* wsrc = (const float4*)Wv;
        float4* wdst = (float4*)Wvs;
#pragma unroll
        for (int u = 0; u < 4; ++u) wdst[t + u * 256] = wsrc[t + u * 256];
        if (t < 64) bvs[t] = bv[t];
    }
    __syncthreads();

    float fac[4];
#pragma unroll
    for (int it = 0; it < 4; ++it) {
        int i = it * 16 + c16;
        float m0 = Msh[i], m1 = Msh[64 + i], m2 = Msh[128 + i], m3 = Msh[192 + i];
        float ms = fmaxf(fmaxf(m0, m1), fmaxf(m2, m3));
        float ls = __expf(m0 - ms) * Lsh[i] + __expf(m1 - ms) * Lsh[64 + i]
                 + __expf(m2 - ms) * Lsh[128 + i] + __expf(m3 - ms) * Lsh[192 + i];
        fac[it] = __expf(m[it] - ms);
        if (w == 0 && quad == 0) Linv[i] = 1.0f / ls;
    }
#pragma unroll
    for (int cm = 0; cm < 4; ++cm)
#pragma unroll
        for (int it = 0; it < 4; ++it) acc[cm][it] *= fac[it];

    // serialized accumulation of rescaled partials into Osh[i][c]
    for (int wv = 0; wv < 4; ++wv) {
        __syncthreads();
        if (w == wv) {
#pragma unroll
            for (int cm = 0; cm < 4; ++cm)
#pragma unroll
                for (int it = 0; it < 4; ++it) {
                    int i = it * 16 + c16;
                    int c = cm * 16 + quad * 4;
                    float4* dstp = (float4*)(Osh + i * 68 + c);
                    f4 v = acc[cm][it];
                    if (wv == 0) {
                        *dstp = make_float4(v[0], v[1], v[2], v[3]);
                    } else {
                        float4 o = *dstp;
                        *dstp = make_float4(o.x + v[0], o.y + v[1], o.z + v[2], o.w + v[3]);
                    }
                }
        }
    }
    __syncthreads();

    // final projection: out[b][c][i0+i] = gamma*(inv_l[i]*Wv·out2 + bv) + x
    {
        int i  = t & 63;
        int cg = t >> 6;
        float inv = Linv[i];
        float res[16];
#pragma unroll
        for (int k = 0; k < 16; ++k) res[k] = 0.f;
#pragma unroll 4
        for (int cb = 0; cb < 16; ++cb) {
            float4 o = *(const float4*)(Osh + i * 68 + cb * 4);
#pragma unroll
            for (int k = 0; k < 16; ++k) {
                float4 wv4 = *(const float4*)(Wvs + (cg * 16 + k) * 64 + cb * 4);
                res[k] = fmaf(wv4.x, o.x, fmaf(wv4.y, o.y, fmaf(wv4.z, o.z, fmaf(wv4.w, o.w, res[k]))));
            }
        }
        float g = gamma[0];
        const float* xr = x + ((size_t)b << 18) + i0;
        float* outp = out + ((size_t)b << 18) + i0;
#pragma unroll
        for (int k = 0; k < 16; ++k) {
            int c = cg * 16 + k;
            float attn = fmaf(res[k], inv, bvs[c]);
            size_t off = ((size_t)c << 12) + i;
            outp[off] = fmaf(g, attn, xr[off]);   // coalesced: lanes = consecutive i
        }
    }
}

extern "C" void kernel_launch(void* const* d_in, const int* in_sizes, int n_in,
                              void* d_out, int out_size, void* d_ws, size_t ws_size,
                              hipStream_t stream) {
    const float* x     = (const float*)d_in[0];
    const float* Wq    = (const float*)d_in[1];
    const float* bq    = (const float*)d_in[2];
    const float* Wk    = (const float*)d_in[3];
    const float* bk    = (const float*)d_in[4];
    const float* Wv    = (const float*)d_in[5];
    const float* bv    = (const float*)d_in[6];
    const float* gamma = (const float*)d_in[7];
    float* out = (float*)d_out;

    // ws layout (bytes): qbf [16384*8*2 = 256KB] | kbf [256KB] | xbf [2MB]
    __hip_bfloat16* qbf = (__hip_bfloat16*)d_ws;
    __hip_bfloat16* kbf = qbf + (size_t)4 * NPIX * 8;
    __hip_bfloat16* xbf = kbf + (size_t)4 * NPIX * 8;

    prep_kernel<<<256, 256, 0, stream>>>(x, Wq, bq, Wk, bk, qbf, kbf, xbf);
    flash_kernel<<<256, 256, 0, stream>>>(qbf, kbf, xbf, Wv, bv, x, gamma, out);
}